// Round 4
// baseline (395.591 us; speedup 1.0000x reference)
//
#include <hip/hip_runtime.h>
#include <math.h>

// x [B=16, C=64, H=256, W=256] fp32 -> out [16,1,256,256] fp32
// out = mean_c sqrt(sobelx^2 + sobely^2 + 1e-12), zero-padded 3x3
#define B_  16
#define C_  64
#define H_  256
#define W_  256
#define R_  16        // output rows per block (halo 18/16 = 1.125x)
#define NW  8         // waves per block (512 threads)
#define CPW (C_/NW)   // 8 channels per wave

// Each wave spans the full 256-col width (lane*4 cols), owns R_=16 output
// rows for its 8 channels. 8 wave-partials combined by a fixed-order
// wave-tree through 64 KB LDS -> deterministic; wave 0 stores the tile.
__global__ __launch_bounds__(512, 2) void sobel_kernel(const float* __restrict__ x,
                                                       float* __restrict__ out) {
    const int lane = threadIdx.x & 63;
    const int wv   = threadIdx.x >> 6;   // 0..7

    // XCD-pair swizzle (heuristic, assumes linear-block-id % 8 XCD round-robin):
    // the two blocks of a strip pair (strips 2p, 2p+1) get the same L&7 ->
    // same XCD, so their 2 shared halo rows/channel can hit that XCD's L2.
    const int L   = blockIdx.y * gridDim.x + blockIdx.x;  // 0..255
    const int xcd = L & 7;
    const int idx = L >> 3;                   // 0..31
    const int P   = xcd * 16 + (idx >> 1);    // strip-pair id 0..127
    const int sub = idx & 1;
    const int b     = P >> 3;                 // 0..15
    const int strip = ((P & 7) << 1) | sub;   // 0..15

    const int w0 = lane * 4;
    const int r0 = strip * R_;

    float4 acc[R_];
#pragma unroll
    for (int r = 0; r < R_; ++r) acc[r] = make_float4(0.f, 0.f, 0.f, 0.f);

    const float* xb = x + ((size_t)b * C_ + wv * CPW) * (size_t)(H_ * W_);

    for (int cc = 0; cc < CPW; ++cc) {
        const float* plane = xb + (size_t)cc * (H_ * W_);

        // Preload all 18 rows unconditionally (clamped index stays in-bounds)
        // -> 18 dwordx4 in flight per wave.
        float4 v[R_ + 2];
#pragma unroll
        for (int rr = 0; rr < R_ + 2; ++rr) {
            int gr  = r0 - 1 + rr;
            int grc = min(max(gr, 0), H_ - 1);
            v[rr] = *(const float4*)(plane + (size_t)grc * W_ + w0);
        }
        if (r0 == 0)        v[0]      = make_float4(0.f, 0.f, 0.f, 0.f);
        if (r0 + R_ == H_)  v[R_ + 1] = make_float4(0.f, 0.f, 0.f, 0.f);

        // Separable Sobel rolling over rows:
        //   s = l + 2m + r (smooth), d = r - l (diff)
        //   ex(row) = d(row-1) + 2 d(row) + d(row+1); ey(row) = s(row+1) - s(row-1)
        float4 s0 = make_float4(0,0,0,0), s1 = s0, d0 = s0, d1 = s0;
#pragma unroll
        for (int rr = 0; rr < R_ + 2; ++rr) {
            float4 vr = v[rr];
            float Lh = __shfl_up(vr.w, 1);
            float Rh = __shfl_down(vr.x, 1);
            if (lane == 0)  Lh = 0.f;   // true W edges (wave spans full width)
            if (lane == 63) Rh = 0.f;

            float4 s2, d2;
            s2.x = Lh   + 2.f*vr.x + vr.y;
            s2.y = vr.x + 2.f*vr.y + vr.z;
            s2.z = vr.y + 2.f*vr.z + vr.w;
            s2.w = vr.z + 2.f*vr.w + Rh;
            d2.x = vr.y - Lh;
            d2.y = vr.z - vr.x;
            d2.z = vr.w - vr.y;
            d2.w = Rh   - vr.z;

            if (rr >= 2) {
                float ex, ey;
                ex = d0.x + 2.f*d1.x + d2.x;  ey = s2.x - s0.x;
                acc[rr-2].x += sqrtf(ex*ex + ey*ey + 1e-12f);
                ex = d0.y + 2.f*d1.y + d2.y;  ey = s2.y - s0.y;
                acc[rr-2].y += sqrtf(ex*ex + ey*ey + 1e-12f);
                ex = d0.z + 2.f*d1.z + d2.z;  ey = s2.z - s0.z;
                acc[rr-2].z += sqrtf(ex*ex + ey*ey + 1e-12f);
                ex = d0.w + 2.f*d1.w + d2.w;  ey = s2.w - s0.w;
                acc[rr-2].w += sqrtf(ex*ex + ey*ey + 1e-12f);
            }
            s0 = s1; s1 = s2;
            d0 = d1; d1 = d2;
        }
    }

    // Fixed-order wave-tree reduction: result = ((w0+w4)+(w2+w6)) + ((w1+w5)+(w3+w7))
    // (any fixed association; bitwise identical across runs -> deterministic).
    __shared__ float part[NW / 2][R_][W_];   // 4*16*256*4 B = 64 KB

    if (wv >= 4) {
#pragma unroll
        for (int r = 0; r < R_; ++r)
            *(float4*)&part[wv - 4][r][w0] = acc[r];
    }
    __syncthreads();
    if (wv < 4) {
#pragma unroll
        for (int r = 0; r < R_; ++r) {
            float4 p = *(const float4*)&part[wv][r][w0];
            acc[r].x += p.x; acc[r].y += p.y; acc[r].z += p.z; acc[r].w += p.w;
        }
    }
    __syncthreads();
    if (wv == 2 || wv == 3) {
#pragma unroll
        for (int r = 0; r < R_; ++r)
            *(float4*)&part[wv - 2][r][w0] = acc[r];
    }
    __syncthreads();
    if (wv < 2) {
#pragma unroll
        for (int r = 0; r < R_; ++r) {
            float4 p = *(const float4*)&part[wv][r][w0];
            acc[r].x += p.x; acc[r].y += p.y; acc[r].z += p.z; acc[r].w += p.w;
        }
    }
    __syncthreads();
    if (wv == 1) {
#pragma unroll
        for (int r = 0; r < R_; ++r)
            *(float4*)&part[0][r][w0] = acc[r];
    }
    __syncthreads();
    if (wv == 0) {
        const float scale = 1.f / (float)C_;
        float* ob = out + ((size_t)b * H_ + r0) * W_ + w0;
#pragma unroll
        for (int r = 0; r < R_; ++r) {
            float4 p = *(const float4*)&part[0][r][w0];
            float4 o;
            o.x = (acc[r].x + p.x) * scale;
            o.y = (acc[r].y + p.y) * scale;
            o.z = (acc[r].z + p.z) * scale;
            o.w = (acc[r].w + p.w) * scale;
            *(float4*)(ob + (size_t)r * W_) = o;
        }
    }
}

extern "C" void kernel_launch(void* const* d_in, const int* in_sizes, int n_in,
                              void* d_out, int out_size, void* d_ws, size_t ws_size,
                              hipStream_t stream) {
    const float* x = (const float*)d_in[0];
    float* out = (float*)d_out;
    dim3 grid(H_ / R_, B_);   // (16, 16) = 256 blocks = 1 per CU
    sobel_kernel<<<grid, 512, 0, stream>>>(x, out);
}